// Round 1
// 178.572 us; speedup vs baseline: 1.1231x; 1.1231x over previous
//
#include <hip/hip_runtime.h>
#include <stdint.h>

#define B_ 8
#define T_ 512
#define M_ 16
#define D_ 128
#define P_ 256
#define H_ 8
#define E_ 32

typedef __attribute__((ext_vector_type(8))) short  short8;
typedef __attribute__((ext_vector_type(4))) short  short4v;
typedef __attribute__((ext_vector_type(4))) float  float4v;
typedef __attribute__((ext_vector_type(2))) unsigned int uint2v;
typedef __attribute__((ext_vector_type(4))) unsigned int uint4v;
typedef __attribute__((ext_vector_type(2))) __bf16 bf16x2;

#define MFMA32(a,b,c) __builtin_amdgcn_mfma_f32_16x16x32_bf16(a,b,c,0,0,0)   // K=32, short8 ops
#define MFMA16(a,b,c) __builtin_amdgcn_mfma_f32_16x16x16bf16_1k(a,b,c,0,0,0) // K=16, short4 ops
#define EXP2F(x) __builtin_amdgcn_exp2f(x)

#define C2 0.2550332772062413f   // log2(e)/sqrt(E)

// cold-path scalar RNE (prep only)
static __device__ __forceinline__ unsigned short f2bf(float x){
  unsigned int u = __builtin_bit_cast(unsigned int, x);
  u += 0x7FFFu + ((u >> 16) & 1u);           // RNE
  return (unsigned short)(u >> 16);
}

// hot-path: plain __bf16 casts -> compiler emits v_cvt_pk_bf16_f32 (RNE).
// (__builtin_amdgcn_cvt_pk_bf16_f32 doesn't exist as a builtin on gfx950;
//  the old f2bf fallback cost ~18 VALU per pack4 and dominated VALUBusy.)
static __device__ __forceinline__ unsigned int pk2(float a, float b){
  bf16x2 h; h[0] = (__bf16)a; h[1] = (__bf16)b;
  return __builtin_bit_cast(unsigned int, h);
}

static __device__ __forceinline__ short4v pack4(float4v v){
  uint2v u; u.x = pk2(v[0], v[1]); u.y = pk2(v[2], v[3]);
  return __builtin_bit_cast(short4v, u);
}

static __device__ __forceinline__ short8 pack8(float4v a, float4v b){
  uint4v u; u.x = pk2(a[0],a[1]); u.y = pk2(a[2],a[3]);
  u.z = pk2(b[0],b[1]); u.w = pk2(b[2],b[3]);
  return __builtin_bit_cast(short8, u);
}

static __device__ __forceinline__ short8 cat44(short4v lo, short4v hi){
  short8 r;
  r[0]=lo[0]; r[1]=lo[1]; r[2]=lo[2]; r[3]=lo[3];
  r[4]=hi[0]; r[5]=hi[1]; r[6]=hi[2]; r[7]=hi[3];
  return r;
}

// ------- kernel 0: WT[z][p][d] bf16 (Wq pre-scaled by C2) + maskf transpose -------
// Q and K weight rows are PERMUTED so each projection pass directly produces the
// e-chunk-of-8 lane layout required by the K=32 MFMA operands:
//   storage row w = eh*16 + q4*4 + r  holds true column  e = q4*8 + eh*4 + r.
__global__ void prep(const float* __restrict__ Wq, const float* __restrict__ Wk,
                     const float* __restrict__ Wv, const int* __restrict__ mask,
                     uint16_t* __restrict__ WT, float* __restrict__ maskf){
  int idx = blockIdx.x*256 + threadIdx.x;      // 640*256 = 163840
  if (idx < 3*P_*D_){                          // 98304: weight transpose+cast
    int d = idx & (D_-1);
    int p = (idx >> 7) & (P_-1);
    int z = idx >> 15;
    int col = p;
    if (z < 2){                                // Q, K: permute within-head rows
      int w = p & 31;
      int e = ((w>>2)&3)*8 + ((w>>4)&1)*4 + (w&3);
      col = (p & ~31) | e;
    }
    const float* W = (z==0) ? Wq : (z==1) ? Wk : Wv;
    float sc = (z==0) ? C2 : 1.0f;
    WT[idx] = f2bf(W[d*P_ + col] * sc);
  } else {                                     // 65536: mask -> maskf[(b*M+m)*T+s]
    int j = idx - 3*P_*D_;
    int s = j & (T_-1);
    int bm = j >> 9;
    int b = bm >> 4, m = bm & (M_-1);
    maskf[j] = mask[(b*T_ + s)*M_ + m] ? 0.0f : -1e30f;
  }
}

// ---------------- fused QKV + masked attention, one block per (b,m,h) ------
// Wave w owns rows [64w,64w+64). Q/K weight-row permutation makes the proj
// C-layout equal the K=32 MFMA operand layout: Q stays in regs as short8,
// K rows are linear-in-e in LDS (16B-slot XOR swizzle -> conflict-free b128
// reads), so S^T = K.Q^T is ONE mfma_16x16x32 per 16x16 tile (was 2x K=16).
// V/PV unchanged (P fragment is already the K=16 A operand lane-locally).
__global__ __launch_bounds__(512, 4) void attn_fused(
    const float* __restrict__ inp, const uint16_t* __restrict__ WT,
    const float* __restrict__ bq, const float* __restrict__ bk,
    const float* __restrict__ bv, const float* __restrict__ maskf,
    float* __restrict__ out){
  __shared__ __align__(16) uint16_t Kb[T_*E_];   // 32768 B  K[s][e] linear-e, slot-swizzled
  __shared__ __align__(16) uint16_t Vt[E_*T_];   // 32768 B  V^T[e][s], u-swizzled

  const int bx = blockIdx.x;                // 1024
  const int h = bx >> 7, bm = bx & 127;     // same-bm blocks -> same XCD (bx%8 = bm%8)
  const int b = bm >> 4, m = bm & 15;
  const int tid = threadIdx.x;
  const int wave = tid >> 6, lane = tid & 63;
  const int q4 = lane >> 4, c = lane & 15;
  const int t0 = wave*64;

  // ---- pack inp rows once: rows t0+tj*16+c, full d ----
  short8 af[4][4];   // [tj][kc]
  for (int tj=0; tj<4; tj++){
    const float* src = inp + (size_t)((b*T_ + t0 + tj*16 + c)*M_ + m)*D_;
    for (int kc=0; kc<4; kc++){
      float4v x0 = *(const float4v*)(src + kc*32 + q4*8);
      float4v x1 = *(const float4v*)(src + kc*32 + q4*8 + 4);
      af[tj][kc] = pack8(x0, x1);
    }
  }

  const uint16_t* WQ = WT                       + (size_t)(h*E_)*D_;
  const uint16_t* WK = WT + (size_t)1*P_*D_     + (size_t)(h*E_)*D_;
  const uint16_t* WV = WT + (size_t)2*P_*D_     + (size_t)(h*E_)*D_;
  float4v zf = {0.f,0.f,0.f,0.f};

  // ---- K projection -> Kb[s][e]: pass eh yields e = q4*8+eh*4+r ----
  // byte addr = s*64 + slot*16 + eh*8, slot = q4 ^ (s&3)  (16B granule XOR)
  for (int eh=0; eh<2; eh++){
    float4v ka[4]; for (int j=0;j<4;j++) ka[j]=zf;
    for (int kc=0; kc<4; kc++){
      short8 w = *(const short8*)(WK + (size_t)(eh*16 + c)*D_ + kc*32 + q4*8);
      for (int sj=0; sj<4; sj++) ka[sj] = MFMA32(w, af[sj][kc], ka[sj]);
    }
    float4v bk4 = *(const float4v*)(bk + h*E_ + q4*8 + eh*4);
    for (int sj=0; sj<4; sj++){
      int s = t0 + sj*16 + c;
      short4v kv = pack4(ka[sj] + bk4);
      *(short4v*)(Kb + s*32 + ((q4 ^ (s&3))<<3) + eh*4) = kv;
    }
  }
  // ---- V projection -> Vt[e][s] (scalar b16 transpose writes, identity e) ----
  for (int eh=0; eh<2; eh++){
    float4v va[4]; for (int j=0;j<4;j++) va[j]=zf;
    for (int kc=0; kc<4; kc++){
      short8 w = *(const short8*)(WV + (size_t)(eh*16 + c)*D_ + kc*32 + q4*8);
      for (int sj=0; sj<4; sj++) va[sj] = MFMA32(w, af[sj][kc], va[sj]);
    }
    float4v bv4 = *(const float4v*)(bv + h*E_ + eh*16 + q4*4);
    for (int sj=0; sj<4; sj++){
      int s = t0 + sj*16 + c;
      short4v vv = pack4(va[sj] + bv4);
      for (int r=0; r<4; r++){
        int e = eh*16 + q4*4 + r;
        Vt[e*T_ + ((((s>>2) + e) & 127)*4) + (s&3)] = (uint16_t)vv[r];
      }
    }
  }
  // ---- Q projection -> q8 regs: concat(pass0,pass1) = e chunk q4*8..q4*8+7 ----
  short8 q8[4];
  {
    short4v qtmp[4][2];
    for (int eh=0; eh<2; eh++){
      float4v qa[4]; for (int j=0;j<4;j++) qa[j]=zf;
      for (int kc=0; kc<4; kc++){
        short8 w = *(const short8*)(WQ + (size_t)(eh*16 + c)*D_ + kc*32 + q4*8);
        for (int tj=0; tj<4; tj++) qa[tj] = MFMA32(w, af[tj][kc], qa[tj]);
      }
      float4v bq4 = *(const float4v*)(bq + h*E_ + q4*8 + eh*4);
      bq4 *= C2;
      for (int tj=0; tj<4; tj++) qtmp[tj][eh] = pack4(qa[tj] + bq4);
    }
    for (int tj=0; tj<4; tj++) q8[tj] = cat44(qtmp[tj][0], qtmp[tj][1]);
  }
  __syncthreads();

  // ---- s-loop: S^T = K.Q^T (mask as C operand) -> exp2 -> PV ----
  float4v O[4][2], L4[4];
  for (int i=0;i<4;i++){ O[i][0]=zf; O[i][1]=zf; L4[i]=zf; }
  const short one_bf = (short)0x3F80;
  short4v ones; ones[0]=one_bf; ones[1]=one_bf; ones[2]=one_bf; ones[3]=one_bf;
  const float* mrow = maskf + (size_t)bm*T_;

  for (int sb=0; sb<16; sb++){
    for (int si=0; si<2; si++){
      const int sq = sb*32 + si*16;
      float4v mm = *(const float4v*)(mrow + sq + q4*4);
      const int srow = sq + c;
      // one b128: K[srow][e = q4*8 .. q4*8+7]; wave covers each 16B slot once
      short8 kb8 = *(const short8*)(Kb + srow*32 + ((q4 ^ (srow&3))<<3));
      const int u = (sq >> 2) + q4;
      short4v vf0 = *(const short4v*)(Vt + (size_t)c*T_      + ((u + c     ) & 127)*4);
      short4v vf1 = *(const short4v*)(Vt + (size_t)(16+c)*T_ + ((u + 16 + c) & 127)*4);
      for (int tj=0; tj<4; tj++){
        float4v st = MFMA32(kb8, q8[tj], mm);
        float4v p;
        p[0] = EXP2F(st[0]);
        p[1] = EXP2F(st[1]);
        p[2] = EXP2F(st[2]);
        p[3] = EXP2F(st[3]);
        short4v pf = pack4(p);
        O[tj][0] = MFMA16(pf, vf0, O[tj][0]);
        O[tj][1] = MFMA16(pf, vf1, O[tj][1]);
        L4[tj]   = MFMA16(pf, ones, L4[tj]);
      }
    }
  }

  // ---- normalize + direct stores (lane = e, regs = t) ----
  for (int ti=0; ti<4; ti++){
    float4v linv;
    for (int r=0; r<4; r++) linv[r] = __builtin_amdgcn_rcpf(L4[ti][r]);
    for (int ej=0; ej<2; ej++){
      float4v v = O[ti][ej] * linv;
      for (int r=0; r<4; r++){
        int t = t0 + ti*16 + q4*4 + r;
        out[(size_t)((b*T_ + t)*M_ + m)*P_ + h*E_ + ej*16 + c] = v[r];
      }
    }
  }
}

extern "C" void kernel_launch(void* const* d_in, const int* in_sizes, int n_in,
                              void* d_out, int out_size, void* d_ws, size_t ws_size,
                              hipStream_t stream){
  const float* inp = (const float*)d_in[0];
  const int*   msk = (const int*)  d_in[1];
  const float* Wq  = (const float*)d_in[2];
  const float* bq  = (const float*)d_in[3];
  const float* Wk  = (const float*)d_in[4];
  const float* bk  = (const float*)d_in[5];
  const float* Wv  = (const float*)d_in[6];
  const float* bv  = (const float*)d_in[7];
  float* out = (float*)d_out;

  uint16_t* WT    = (uint16_t*)d_ws;                       // 196,608 B
  float*    maskf = (float*)((char*)d_ws + 196608);        // 262,144 B

  prep<<<dim3(640), dim3(256), 0, stream>>>(Wq, Wk, Wv, msk, WT, maskf);
  attn_fused<<<dim3(1024), dim3(512), 0, stream>>>(inp, WT, bq, bk, bv, maskf, out);
}

// Round 2
// 176.031 us; speedup vs baseline: 1.1393x; 1.0144x over previous
//
#include <hip/hip_runtime.h>
#include <stdint.h>

#define B_ 8
#define T_ 512
#define M_ 16
#define D_ 128
#define P_ 256
#define H_ 8
#define E_ 32

typedef __attribute__((ext_vector_type(8))) short  short8;
typedef __attribute__((ext_vector_type(4))) short  short4v;
typedef __attribute__((ext_vector_type(4))) float  float4v;
typedef __attribute__((ext_vector_type(2))) unsigned int uint2v;
typedef __attribute__((ext_vector_type(4))) unsigned int uint4v;
typedef __attribute__((ext_vector_type(2))) __bf16 bf16x2;

#define MFMA32(a,b,c) __builtin_amdgcn_mfma_f32_16x16x32_bf16(a,b,c,0,0,0)   // K=32, short8 ops
#define EXP2F(x) __builtin_amdgcn_exp2f(x)

#define C2 0.2550332772062413f   // log2(e)/sqrt(E)

// cold-path scalar RNE (prep only)
static __device__ __forceinline__ unsigned short f2bf(float x){
  unsigned int u = __builtin_bit_cast(unsigned int, x);
  u += 0x7FFFu + ((u >> 16) & 1u);           // RNE
  return (unsigned short)(u >> 16);
}

// hot-path: plain __bf16 casts -> compiler emits v_cvt_pk_bf16_f32 (RNE).
static __device__ __forceinline__ unsigned int pk2(float a, float b){
  bf16x2 h; h[0] = (__bf16)a; h[1] = (__bf16)b;
  return __builtin_bit_cast(unsigned int, h);
}

static __device__ __forceinline__ short4v pack4(float4v v){
  uint2v u; u.x = pk2(v[0], v[1]); u.y = pk2(v[2], v[3]);
  return __builtin_bit_cast(short4v, u);
}

static __device__ __forceinline__ short8 pack8(float4v a, float4v b){
  uint4v u; u.x = pk2(a[0],a[1]); u.y = pk2(a[2],a[3]);
  u.z = pk2(b[0],b[1]); u.w = pk2(b[2],b[3]);
  return __builtin_bit_cast(short8, u);
}

static __device__ __forceinline__ short8 cat44(short4v lo, short4v hi){
  short8 r;
  r[0]=lo[0]; r[1]=lo[1]; r[2]=lo[2]; r[3]=lo[3];
  r[4]=hi[0]; r[5]=hi[1]; r[6]=hi[2]; r[7]=hi[3];
  return r;
}

// ------- kernel 0: WT[z][p][d] bf16 (Wq pre-scaled by C2) + maskf transpose -------
// Q and K weight rows are PERMUTED so each projection pass directly produces the
// e-chunk-of-8 lane layout required by the K=32 MFMA operands:
//   storage row w = eh*16 + q4*4 + r  holds true column  e = q4*8 + eh*4 + r.
__global__ void prep(const float* __restrict__ Wq, const float* __restrict__ Wk,
                     const float* __restrict__ Wv, const int* __restrict__ mask,
                     uint16_t* __restrict__ WT, float* __restrict__ maskf){
  int idx = blockIdx.x*256 + threadIdx.x;      // 640*256 = 163840
  if (idx < 3*P_*D_){                          // 98304: weight transpose+cast
    int d = idx & (D_-1);
    int p = (idx >> 7) & (P_-1);
    int z = idx >> 15;
    int col = p;
    if (z < 2){                                // Q, K: permute within-head rows
      int w = p & 31;
      int e = ((w>>2)&3)*8 + ((w>>4)&1)*4 + (w&3);
      col = (p & ~31) | e;
    }
    const float* W = (z==0) ? Wq : (z==1) ? Wk : Wv;
    float sc = (z==0) ? C2 : 1.0f;
    WT[idx] = f2bf(W[d*P_ + col] * sc);
  } else {                                     // 65536: mask -> maskf[(b*M+m)*T+s]
    int j = idx - 3*P_*D_;
    int s = j & (T_-1);
    int bm = j >> 9;
    int b = bm >> 4, m = bm & (M_-1);
    maskf[j] = mask[(b*T_ + s)*M_ + m] ? 0.0f : -1e30f;
  }
}

// ---------------- fused QKV + masked attention, one block per (b,m,h) ------
// Wave w owns rows [64w,64w+64). All MFMAs are K=32 (the legacy 16x16x16_1k
// opcode measured ~4-6x its theoretical cost on gfx950 and is eliminated):
//  - QK: one mfma_16x16x32 per 16x16 S^T tile (round-1 weight-permute trick).
//  - PV+L: the MFMA k-index is a free summation label -- the P fragment's
//    natural per-lane s-order {si0 quad, si1 quad} is a legal K=32 A-operand
//    as long as B (V) supplies the SAME s-order, which cat44 of the two
//    existing per-si Vt quad reads provides. Zero cross-lane shuffles.
__global__ __launch_bounds__(512, 4) void attn_fused(
    const float* __restrict__ inp, const uint16_t* __restrict__ WT,
    const float* __restrict__ bq, const float* __restrict__ bk,
    const float* __restrict__ bv, const float* __restrict__ maskf,
    float* __restrict__ out){
  __shared__ __align__(16) uint16_t Kb[T_*E_];   // 32768 B  K[s][e] linear-e, slot-swizzled
  __shared__ __align__(16) uint16_t Vt[E_*T_];   // 32768 B  V^T[e][s], u-swizzled

  const int bx = blockIdx.x;                // 1024
  const int h = bx >> 7, bm = bx & 127;     // same-bm blocks -> same XCD (bx%8 = bm%8)
  const int b = bm >> 4, m = bm & 15;
  const int tid = threadIdx.x;
  const int wave = tid >> 6, lane = tid & 63;
  const int q4 = lane >> 4, c = lane & 15;
  const int t0 = wave*64;

  // ---- pack inp rows once: rows t0+tj*16+c, full d ----
  short8 af[4][4];   // [tj][kc]
  for (int tj=0; tj<4; tj++){
    const float* src = inp + (size_t)((b*T_ + t0 + tj*16 + c)*M_ + m)*D_;
    for (int kc=0; kc<4; kc++){
      float4v x0 = *(const float4v*)(src + kc*32 + q4*8);
      float4v x1 = *(const float4v*)(src + kc*32 + q4*8 + 4);
      af[tj][kc] = pack8(x0, x1);
    }
  }

  const uint16_t* WQ = WT                       + (size_t)(h*E_)*D_;
  const uint16_t* WK = WT + (size_t)1*P_*D_     + (size_t)(h*E_)*D_;
  const uint16_t* WV = WT + (size_t)2*P_*D_     + (size_t)(h*E_)*D_;
  float4v zf = {0.f,0.f,0.f,0.f};

  // ---- K projection -> Kb[s][e]: pass eh yields e = q4*8+eh*4+r ----
  // byte addr = s*64 + slot*16 + eh*8, slot = q4 ^ (s&3)  (16B granule XOR)
  for (int eh=0; eh<2; eh++){
    float4v ka[4]; for (int j=0;j<4;j++) ka[j]=zf;
    for (int kc=0; kc<4; kc++){
      short8 w = *(const short8*)(WK + (size_t)(eh*16 + c)*D_ + kc*32 + q4*8);
      for (int sj=0; sj<4; sj++) ka[sj] = MFMA32(w, af[sj][kc], ka[sj]);
    }
    float4v bk4 = *(const float4v*)(bk + h*E_ + q4*8 + eh*4);
    for (int sj=0; sj<4; sj++){
      int s = t0 + sj*16 + c;
      short4v kv = pack4(ka[sj] + bk4);
      *(short4v*)(Kb + s*32 + ((q4 ^ (s&3))<<3) + eh*4) = kv;
    }
  }
  // ---- V projection -> Vt[e][s] (scalar b16 transpose writes, identity e) ----
  for (int eh=0; eh<2; eh++){
    float4v va[4]; for (int j=0;j<4;j++) va[j]=zf;
    for (int kc=0; kc<4; kc++){
      short8 w = *(const short8*)(WV + (size_t)(eh*16 + c)*D_ + kc*32 + q4*8);
      for (int sj=0; sj<4; sj++) va[sj] = MFMA32(w, af[sj][kc], va[sj]);
    }
    float4v bv4 = *(const float4v*)(bv + h*E_ + eh*16 + q4*4);
    for (int sj=0; sj<4; sj++){
      int s = t0 + sj*16 + c;
      short4v vv = pack4(va[sj] + bv4);
      for (int r=0; r<4; r++){
        int e = eh*16 + q4*4 + r;
        Vt[e*T_ + ((((s>>2) + e) & 127)*4) + (s&3)] = (uint16_t)vv[r];
      }
    }
  }
  // ---- Q projection -> q8 regs: concat(pass0,pass1) = e chunk q4*8..q4*8+7 ----
  short8 q8[4];
  {
    short4v qtmp[4][2];
    for (int eh=0; eh<2; eh++){
      float4v qa[4]; for (int j=0;j<4;j++) qa[j]=zf;
      for (int kc=0; kc<4; kc++){
        short8 w = *(const short8*)(WQ + (size_t)(eh*16 + c)*D_ + kc*32 + q4*8);
        for (int tj=0; tj<4; tj++) qa[tj] = MFMA32(w, af[tj][kc], qa[tj]);
      }
      float4v bq4 = *(const float4v*)(bq + h*E_ + q4*8 + eh*4);
      bq4 *= C2;
      for (int tj=0; tj<4; tj++) qtmp[tj][eh] = pack4(qa[tj] + bq4);
    }
    for (int tj=0; tj<4; tj++) q8[tj] = cat44(qtmp[tj][0], qtmp[tj][1]);
  }
  __syncthreads();

  // ---- s-loop: 32 s per iteration. S^T = K.Q^T (mask as C) -> exp2 -> PV ----
  float4v O[4][2], L4[4];
  for (int i=0;i<4;i++){ O[i][0]=zf; O[i][1]=zf; L4[i]=zf; }
  const short one_bf = (short)0x3F80;
  short8 ones8;
  for (int i=0;i<8;i++) ones8[i] = one_bf;
  const float* mrow = maskf + (size_t)bm*T_;

  for (int sb=0; sb<16; sb++){
    const int sq = sb*32;
    // mask (C operand) for both 16-row subtiles
    float4v mm0 = *(const float4v*)(mrow + sq + q4*4);
    float4v mm1 = *(const float4v*)(mrow + sq + 16 + q4*4);
    // K rows for both subtiles (one b128 each, conflict-free slot swizzle)
    const int srow0 = sq + c, srow1 = sq + 16 + c;
    short8 kb8_0 = *(const short8*)(Kb + srow0*32 + ((q4 ^ (srow0&3))<<3));
    short8 kb8_1 = *(const short8*)(Kb + srow1*32 + ((q4 ^ (srow1&3))<<3));
    // V quads in the SAME s-order as the P fragment's k-slots:
    //   k-slot q4*8+i  <->  s = sq + (i<4 ? q4*4+i : 16+q4*4+(i-4))
    const int u0 = sb*8 + q4, u1 = u0 + 4;
    short4v vA0 = *(const short4v*)(Vt + (size_t)c*T_      + ((u0 + c     ) & 127)*4);
    short4v vA1 = *(const short4v*)(Vt + (size_t)c*T_      + ((u1 + c     ) & 127)*4);
    short4v vB0 = *(const short4v*)(Vt + (size_t)(16+c)*T_ + ((u0 + 16 + c) & 127)*4);
    short4v vB1 = *(const short4v*)(Vt + (size_t)(16+c)*T_ + ((u1 + 16 + c) & 127)*4);
    short8 V8_0 = cat44(vA0, vA1);   // e 0..15
    short8 V8_1 = cat44(vB0, vB1);   // e 16..31
    for (int tj=0; tj<4; tj++){
      float4v st0 = MFMA32(kb8_0, q8[tj], mm0);
      float4v st1 = MFMA32(kb8_1, q8[tj], mm1);
      float4v p0, p1;
      p0[0] = EXP2F(st0[0]); p0[1] = EXP2F(st0[1]);
      p0[2] = EXP2F(st0[2]); p0[3] = EXP2F(st0[3]);
      p1[0] = EXP2F(st1[0]); p1[1] = EXP2F(st1[1]);
      p1[2] = EXP2F(st1[2]); p1[3] = EXP2F(st1[3]);
      short8 A8 = pack8(p0, p1);     // k-slots: [si0 quad | si1 quad]
      O[tj][0] = MFMA32(A8, V8_0, O[tj][0]);
      O[tj][1] = MFMA32(A8, V8_1, O[tj][1]);
      L4[tj]   = MFMA32(A8, ones8, L4[tj]);
    }
  }

  // ---- normalize + direct stores (lane = e, regs = t) ----
  for (int ti=0; ti<4; ti++){
    float4v linv;
    for (int r=0; r<4; r++) linv[r] = __builtin_amdgcn_rcpf(L4[ti][r]);
    for (int ej=0; ej<2; ej++){
      float4v v = O[ti][ej] * linv;
      for (int r=0; r<4; r++){
        int t = t0 + ti*16 + q4*4 + r;
        out[(size_t)((b*T_ + t)*M_ + m)*P_ + h*E_ + ej*16 + c] = v[r];
      }
    }
  }
}

extern "C" void kernel_launch(void* const* d_in, const int* in_sizes, int n_in,
                              void* d_out, int out_size, void* d_ws, size_t ws_size,
                              hipStream_t stream){
  const float* inp = (const float*)d_in[0];
  const int*   msk = (const int*)  d_in[1];
  const float* Wq  = (const float*)d_in[2];
  const float* bq  = (const float*)d_in[3];
  const float* Wk  = (const float*)d_in[4];
  const float* bk  = (const float*)d_in[5];
  const float* Wv  = (const float*)d_in[6];
  const float* bv  = (const float*)d_in[7];
  float* out = (float*)d_out;

  uint16_t* WT    = (uint16_t*)d_ws;                       // 196,608 B
  float*    maskf = (float*)((char*)d_ws + 196608);        // 262,144 B

  prep<<<dim3(640), dim3(256), 0, stream>>>(Wq, Wk, Wv, msk, WT, maskf);
  attn_fused<<<dim3(1024), dim3(512), 0, stream>>>(inp, WT, bq, bk, bv, maskf, out);
}